// Round 1
// 849.238 us; speedup vs baseline: 1.2114x; 1.2114x over previous
//
#include <hip/hip_runtime.h>
#include <stdint.h>

#define S_ 2048
#define R_ 512
#define C_ 64

typedef unsigned short u16;
typedef __attribute__((ext_vector_type(8))) short bf8_t;   // 8 bf16 (4 VGPRs)
typedef __attribute__((ext_vector_type(4))) float f4_t;    // 4 fp32 acc

__device__ __forceinline__ u16 f2b(float f) {  // f32 -> bf16 RNE
    union { float f; unsigned int i; } x; x.f = f;
    unsigned int r = x.i + 0x7fffu + ((x.i >> 16) & 1u);
    return (u16)(r >> 16);
}
__device__ __forceinline__ unsigned int pack2(float a, float b) {
    return (unsigned int)f2b(a) | ((unsigned int)f2b(b) << 16);
}
__device__ __forceinline__ void u4_to_f8(uint4 p, float* f) {  // 8 bf16 -> 8 f32
    union { unsigned int i; float f; } x;
    x.i = p.x << 16;         f[0] = x.f;
    x.i = p.x & 0xffff0000u; f[1] = x.f;
    x.i = p.y << 16;         f[2] = x.f;
    x.i = p.y & 0xffff0000u; f[3] = x.f;
    x.i = p.z << 16;         f[4] = x.f;
    x.i = p.z & 0xffff0000u; f[5] = x.f;
    x.i = p.w << 16;         f[6] = x.f;
    x.i = p.w & 0xffff0000u; f[7] = x.f;
}

// ---------------- K0: one-time weight pre-convert to bf16 (B^T fragment layouts) ----
// grid: 32 blocks x 256 threads = 8192 threads
__global__ __launch_bounds__(256) void k0(
    const float* __restrict__ Wk, const float* __restrict__ Wv,
    const float* __restrict__ Wg, const float* __restrict__ Wo,
    u16* __restrict__ kvT, u16* __restrict__ WgT, u16* __restrict__ WoT)
{
    int i = blockIdx.x * 256 + threadIdx.x;      // 0..8191
    if (i < 2048) {                              // kvT[j][c], j in [0,32): k heads then v
        int j = i >> 6, c = i & 63;
        float w = (j < 16) ? Wk[c * 16 + j] : Wv[c * 16 + (j - 16)];
        kvT[i] = f2b(w);
    }
    {                                            // WgT[hc][c] = Wg[c][hc]
        int hc = i >> 6, c = i & 63;
        WgT[i] = f2b(Wg[c * 128 + hc]);
    }
    {                                            // WoT[c][hc] = Wo[hc][c]
        int c = i >> 7, hc = i & 127;
        WoT[i] = f2b(Wo[hc * 64 + c]);
    }
}

// ---------------- K1a: LN + qsum + (k,v) = mn @ [Wk|Wv] via MFMA ----------------
// grid: 32768 blocks (512 r x 64 s-chunks of 32 tokens), 256 threads
__global__ __launch_bounds__(256) void k1a(
    const float* __restrict__ m, const float* __restrict__ mask,
    const float* __restrict__ lnw_g, const float* __restrict__ lnb_g,
    const u16* __restrict__ kvT_g,
    u16* __restrict__ kbuf, u16* __restrict__ vbuf,
    float* __restrict__ qsum, float* __restrict__ msum,
    u16* __restrict__ mns_g)          // may be null (ws too small)
{
    __shared__ __attribute__((aligned(16))) u16 mns[32 * 72];   // [tok][c] bf16, pitch 72
    __shared__ __attribute__((aligned(16))) u16 kva[32 * 40];   // staging [tok][32] bf16
    __shared__ float qred[4][64];
    __shared__ float msred[4];

    const int tid = threadIdx.x;
    const int bi  = blockIdx.x;
    const int r   = bi >> 6;
    const int s0  = (bi & 63) << 5;
    const int wv = tid >> 6, lane = tid & 63;
    const int r16 = lane & 15, quad = lane >> 4;
    const int mt = wv & 1, nt = wv >> 1;

    // B fragments straight from global bf16 (L2-resident) — no LDS weight staging
    bf8_t b0 = *(const bf8_t*)&kvT_g[(nt * 16 + r16) * 64 + quad * 8];
    bf8_t b1 = *(const bf8_t*)&kvT_g[(nt * 16 + r16) * 64 + 32 + quad * 8];

    const int g = tid >> 4, l = tid & 15;
    const float4 lw4 = *(const float4*)&lnw_g[4 * l];
    const float4 lb4 = *(const float4*)&lnb_g[4 * l];

    float4 qacc = {0.f, 0.f, 0.f, 0.f};
    float msacc = 0.f;
    #pragma unroll
    for (int tt = 0; tt < 2; ++tt) {
        int t = g + tt * 16;
        int s = s0 + t;
        size_t base = ((size_t)s * R_ + r) * C_;
        float4 x = *(const float4*)&m[base + 4 * l];
        float sum = x.x + x.y + x.z + x.w;
        float ssq = x.x * x.x + x.y * x.y + x.z * x.z + x.w * x.w;
        #pragma unroll
        for (int off = 1; off <= 8; off <<= 1) {
            sum += __shfl_xor(sum, off);
            ssq += __shfl_xor(ssq, off);
        }
        float mu  = sum * (1.f / 64.f);
        float var = ssq * (1.f / 64.f) - mu * mu;
        float rs  = rsqrtf(var + 1e-5f);
        float4 mn;
        mn.x = (x.x - mu) * rs * lw4.x + lb4.x;
        mn.y = (x.y - mu) * rs * lw4.y + lb4.y;
        mn.z = (x.z - mu) * rs * lw4.z + lb4.z;
        mn.w = (x.w - mu) * rs * lw4.w + lb4.w;
        float mk = mask[(size_t)s * R_ + r];
        qacc.x += mn.x * mk; qacc.y += mn.y * mk;
        qacc.z += mn.z * mk; qacc.w += mn.w * mk;
        if (l == 0) msacc += mk;
        uint2 p; p.x = pack2(mn.x, mn.y); p.y = pack2(mn.z, mn.w);
        *(uint2*)&mns[t * 72 + 4 * l] = p;
        if (mns_g)   // persist normalized tokens for k2 (bf16, [r][s][c])
            *(uint2*)&mns_g[((size_t)r * S_ + s) * C_ + 4 * l] = p;
    }
    // reduce qacc across the 4 groups of each wave
    qacc.x += __shfl_xor(qacc.x, 16); qacc.y += __shfl_xor(qacc.y, 16);
    qacc.z += __shfl_xor(qacc.z, 16); qacc.w += __shfl_xor(qacc.w, 16);
    qacc.x += __shfl_xor(qacc.x, 32); qacc.y += __shfl_xor(qacc.y, 32);
    qacc.z += __shfl_xor(qacc.z, 32); qacc.w += __shfl_xor(qacc.w, 32);
    msacc += __shfl_xor(msacc, 16);  msacc += __shfl_xor(msacc, 32);
    if (lane < 16) *(float4*)&qred[wv][4 * lane] = qacc;
    if (lane == 0) msred[wv] = msacc;
    __syncthreads();

    // MFMA: wave wv -> tile (mt, nt); K=64 in 2 steps; B already in registers
    {
        f4_t acc = {0.f, 0.f, 0.f, 0.f};
        bf8_t a0 = *(const bf8_t*)&mns[(mt * 16 + r16) * 72 + quad * 8];
        bf8_t a1 = *(const bf8_t*)&mns[(mt * 16 + r16) * 72 + 32 + quad * 8];
        acc = __builtin_amdgcn_mfma_f32_16x16x32_bf16(a0, b0, acc, 0, 0, 0);
        acc = __builtin_amdgcn_mfma_f32_16x16x32_bf16(a1, b1, acc, 0, 0, 0);
        #pragma unroll
        for (int i = 0; i < 4; ++i) {
            int row = mt * 16 + quad * 4 + i;
            kva[row * 40 + nt * 16 + r16] = f2b(acc[i]);
        }
    }
    __syncthreads();

    // coalesced copy to kbuf/vbuf + qsum/msum atomics
    for (int uidx = tid; uidx < 512; uidx += 256) {
        int t = uidx >> 4, u = uidx & 15;
        unsigned int val = *(const unsigned int*)&kva[t * 40 + u * 2];
        int s = s0 + t;
        size_t tb = ((size_t)r * S_ + s) * 16;
        if (u < 8) *(unsigned int*)&kbuf[tb + u * 2] = val;
        else       *(unsigned int*)&vbuf[tb + (u - 8) * 2] = val;
    }
    if (tid < 64) {
        float tot = qred[0][tid] + qred[1][tid] + qred[2][tid] + qred[3][tid];
        atomicAdd(&qsum[r * 64 + tid], tot);
    }
    if (tid == 0) atomicAdd(&msum[r], msred[0] + msred[1] + msred[2] + msred[3]);
}

// ---------------- K1b: q + global-softmax pooled attention -> opool ----------------
// grid: 512 blocks (one per r), 256 threads (wave w -> heads w and w+4)
__global__ __launch_bounds__(256) void k1b(
    const float* __restrict__ qsum, const float* __restrict__ msum,
    const float* __restrict__ Wq, const float* __restrict__ mask,
    const u16* __restrict__ kbuf, const u16* __restrict__ vbuf,
    float* __restrict__ opool)
{
    __shared__ float qbar[64];
    __shared__ float qh[128];
    const int tid = threadIdx.x;
    const int r   = blockIdx.x;

    if (tid < 64) qbar[tid] = qsum[r * 64 + tid] / (msum[r] + 1e-10f);
    __syncthreads();
    if (tid < 128) {
        float a = 0.f;
        #pragma unroll 8
        for (int c = 0; c < 64; ++c) a += qbar[c] * Wq[c * 128 + tid];
        qh[tid] = a * 0.25f;   // CH^-0.5
    }
    __syncthreads();

    const int wv = tid >> 6, lane = tid & 63;
    const int h0 = wv, h1 = wv + 4;
    float qa[16], qb[16];
    #pragma unroll
    for (int ch = 0; ch < 16; ++ch) { qa[ch] = qh[h0 * 16 + ch]; qb[ch] = qh[h1 * 16 + ch]; }

    // sweep 1: max
    float m0 = -1e30f, m1 = -1e30f;
    for (int i = 0; i < 32; ++i) {
        int s = i * 64 + lane;
        size_t tb = ((size_t)r * S_ + s) * 16;
        float kf[16];
        u4_to_f8(*(const uint4*)&kbuf[tb], kf);
        u4_to_f8(*(const uint4*)&kbuf[tb + 8], kf + 8);
        float bias = (mask[(size_t)s * R_ + r] - 1.f) * 1e9f;
        float a0 = bias, a1 = bias;
        #pragma unroll
        for (int ch = 0; ch < 16; ++ch) { a0 += qa[ch] * kf[ch]; a1 += qb[ch] * kf[ch]; }
        m0 = fmaxf(m0, a0); m1 = fmaxf(m1, a1);
    }
    #pragma unroll
    for (int off = 1; off < 64; off <<= 1) {
        m0 = fmaxf(m0, __shfl_xor(m0, off));
        m1 = fmaxf(m1, __shfl_xor(m1, off));
    }
    // sweep 2: sum + weighted V
    float l0 = 0.f, l1 = 0.f;
    float o0[16], o1[16];
    #pragma unroll
    for (int ch = 0; ch < 16; ++ch) { o0[ch] = 0.f; o1[ch] = 0.f; }
    for (int i = 0; i < 32; ++i) {
        int s = i * 64 + lane;
        size_t tb = ((size_t)r * S_ + s) * 16;
        float kf[16], vf[16];
        u4_to_f8(*(const uint4*)&kbuf[tb], kf);
        u4_to_f8(*(const uint4*)&kbuf[tb + 8], kf + 8);
        u4_to_f8(*(const uint4*)&vbuf[tb], vf);
        u4_to_f8(*(const uint4*)&vbuf[tb + 8], vf + 8);
        float bias = (mask[(size_t)s * R_ + r] - 1.f) * 1e9f;
        float a0 = bias, a1 = bias;
        #pragma unroll
        for (int ch = 0; ch < 16; ++ch) { a0 += qa[ch] * kf[ch]; a1 += qb[ch] * kf[ch]; }
        float w0 = expf(a0 - m0), w1 = expf(a1 - m1);
        l0 += w0; l1 += w1;
        #pragma unroll
        for (int ch = 0; ch < 16; ++ch) { o0[ch] += w0 * vf[ch]; o1[ch] += w1 * vf[ch]; }
    }
    #pragma unroll
    for (int off = 1; off < 64; off <<= 1) {
        l0 += __shfl_xor(l0, off); l1 += __shfl_xor(l1, off);
        #pragma unroll
        for (int ch = 0; ch < 16; ++ch) {
            o0[ch] += __shfl_xor(o0[ch], off);
            o1[ch] += __shfl_xor(o1[ch], off);
        }
    }
    if (lane == 0) {
        float inv0 = 1.f / l0, inv1 = 1.f / l1;
        #pragma unroll
        for (int ch = 0; ch < 16; ++ch) {
            opool[r * 128 + h0 * 16 + ch] = o0[ch] * inv0;
            opool[r * 128 + h1 * 16 + ch] = o1[ch] * inv1;
        }
    }
}

// ---------------- K2m: g=sigmoid(mns@Wg+bg), out = (opool*g)@Wo + bo ----------------
// reads persisted bf16 mns; weights live in registers; no LN, no weight staging
// grid: 32768 blocks (512 r x 64 s-chunks of 32 tokens), 256 threads
__global__ __launch_bounds__(256) void k2m(
    const u16* __restrict__ mns_g,
    const u16* __restrict__ WgT_g, const u16* __restrict__ WoT_g,
    const float* __restrict__ bg, const float* __restrict__ bo,
    const float* __restrict__ opool, float* __restrict__ out)
{
    __shared__ __attribute__((aligned(16))) u16 olds[32 * 136];  // [tok][hc] bf16
    __shared__ __attribute__((aligned(16))) float outs[32 * 68]; // [tok][c] f32
    __shared__ float opl[128], bgl[128];
    __shared__ float bol[64];

    const int tid = threadIdx.x;
    const int bi  = blockIdx.x;
    const int r   = bi >> 6;
    const int s0  = (bi & 63) << 5;
    const int wv = tid >> 6, lane = tid & 63;
    const int r16 = lane & 15, quad = lane >> 4;

    // wave tile mapping (identical coverage to previous kernel):
    const int mt  = wv >> 1;          // token sub-tile for both steps
    const int nb2 = (wv & 1) * 4;     // step2: nt = nb2..nb2+3
    const int nb3 = (wv & 1) * 2;     // step3: nt = nb3..nb3+1

    // B fragments in registers (16 x 16B loads from L2-resident bf16 weights)
    bf8_t wg[4][2], wo[2][4];
    #pragma unroll
    for (int i = 0; i < 4; ++i)
        #pragma unroll
        for (int kt = 0; kt < 2; ++kt)
            wg[i][kt] = *(const bf8_t*)&WgT_g[((nb2 + i) * 16 + r16) * 64 + kt * 32 + quad * 8];
    #pragma unroll
    for (int i = 0; i < 2; ++i)
        #pragma unroll
        for (int kt = 0; kt < 4; ++kt)
            wo[i][kt] = *(const bf8_t*)&WoT_g[((nb3 + i) * 16 + r16) * 128 + kt * 32 + quad * 8];

    // A fragments for step2 straight from global mns (L3-resident)
    size_t abase = ((size_t)r * S_ + s0 + mt * 16 + r16) * C_;
    bf8_t a0 = *(const bf8_t*)&mns_g[abase + quad * 8];
    bf8_t a1 = *(const bf8_t*)&mns_g[abase + 32 + quad * 8];

    if (tid < 128) { opl[tid] = opool[r * 128 + tid]; bgl[tid] = bg[tid]; }
    if (tid < 64)  { bol[tid] = bo[tid]; }
    __syncthreads();

    // step 2: z = mns[32x64] @ Wg[64x128]; sigmoid gate; olds = opool*g (bf16)
    #pragma unroll
    for (int i = 0; i < 4; ++i) {
        f4_t acc = {0.f, 0.f, 0.f, 0.f};
        acc = __builtin_amdgcn_mfma_f32_16x16x32_bf16(a0, wg[i][0], acc, 0, 0, 0);
        acc = __builtin_amdgcn_mfma_f32_16x16x32_bf16(a1, wg[i][1], acc, 0, 0, 0);
        int hc = (nb2 + i) * 16 + r16;
        float og = opl[hc], bgv = bgl[hc];
        #pragma unroll
        for (int ii = 0; ii < 4; ++ii) {
            int row = mt * 16 + quad * 4 + ii;
            float z  = acc[ii] + bgv;
            float gv = 1.f / (1.f + expf(-z));
            olds[row * 136 + hc] = f2b(og * gv);
        }
    }
    __syncthreads();

    // step 3: out = o[32x128] @ Wo[128x64]
    #pragma unroll
    for (int i = 0; i < 2; ++i) {
        f4_t acc = {0.f, 0.f, 0.f, 0.f};
        #pragma unroll
        for (int kt = 0; kt < 4; ++kt) {
            bf8_t a = *(const bf8_t*)&olds[(mt * 16 + r16) * 136 + kt * 32 + quad * 8];
            acc = __builtin_amdgcn_mfma_f32_16x16x32_bf16(a, wo[i][kt], acc, 0, 0, 0);
        }
        int c = (nb3 + i) * 16 + r16;
        float bov = bol[c];
        #pragma unroll
        for (int ii = 0; ii < 4; ++ii) {
            int row = mt * 16 + quad * 4 + ii;
            outs[row * 68 + c] = acc[ii] + bov;
        }
    }
    __syncthreads();

    // coalesced f32 store: out[s][r][c]
    const int g = tid >> 4, l = tid & 15;
    #pragma unroll
    for (int tt = 0; tt < 2; ++tt) {
        int t = g + tt * 16;
        int s = s0 + t;
        size_t base = ((size_t)s * R_ + r) * C_;
        *(float4*)&out[base + 4 * l] = *(const float4*)&outs[t * 68 + 4 * l];
    }
}

// ---------------- K2f: fallback (ws too small for mns) — LN from m, reg weights ----
__global__ __launch_bounds__(256) void k2f(
    const float* __restrict__ m,
    const float* __restrict__ lnw_g, const float* __restrict__ lnb_g,
    const u16* __restrict__ WgT_g, const u16* __restrict__ WoT_g,
    const float* __restrict__ bg, const float* __restrict__ bo,
    const float* __restrict__ opool, float* __restrict__ out)
{
    __shared__ __attribute__((aligned(16))) u16 mns[32 * 72];    // [tok][c] bf16
    __shared__ __attribute__((aligned(16))) u16 olds[32 * 136];  // [tok][hc] bf16
    __shared__ __attribute__((aligned(16))) float outs[32 * 68]; // [tok][c] f32
    __shared__ float opl[128], bgl[128];
    __shared__ float bol[64];

    const int tid = threadIdx.x;
    const int bi  = blockIdx.x;
    const int r   = bi >> 6;
    const int s0  = (bi & 63) << 5;
    const int wv = tid >> 6, lane = tid & 63;
    const int r16 = lane & 15, quad = lane >> 4;
    const int mt  = wv >> 1;
    const int nb2 = (wv & 1) * 4;
    const int nb3 = (wv & 1) * 2;

    bf8_t wg[4][2], wo[2][4];
    #pragma unroll
    for (int i = 0; i < 4; ++i)
        #pragma unroll
        for (int kt = 0; kt < 2; ++kt)
            wg[i][kt] = *(const bf8_t*)&WgT_g[((nb2 + i) * 16 + r16) * 64 + kt * 32 + quad * 8];
    #pragma unroll
    for (int i = 0; i < 2; ++i)
        #pragma unroll
        for (int kt = 0; kt < 4; ++kt)
            wo[i][kt] = *(const bf8_t*)&WoT_g[((nb3 + i) * 16 + r16) * 128 + kt * 32 + quad * 8];

    if (tid < 128) { opl[tid] = opool[r * 128 + tid]; bgl[tid] = bg[tid]; }
    if (tid < 64)  { bol[tid] = bo[tid]; }

    const int g = tid >> 4, l = tid & 15;
    const float4 lw4 = *(const float4*)&lnw_g[4 * l];
    const float4 lb4 = *(const float4*)&lnb_g[4 * l];
    #pragma unroll
    for (int tt = 0; tt < 2; ++tt) {
        int t = g + tt * 16;
        int s = s0 + t;
        size_t base = ((size_t)s * R_ + r) * C_;
        float4 x = *(const float4*)&m[base + 4 * l];
        float sum = x.x + x.y + x.z + x.w;
        float ssq = x.x * x.x + x.y * x.y + x.z * x.z + x.w * x.w;
        #pragma unroll
        for (int off = 1; off <= 8; off <<= 1) {
            sum += __shfl_xor(sum, off);
            ssq += __shfl_xor(ssq, off);
        }
        float mu  = sum * (1.f / 64.f);
        float var = ssq * (1.f / 64.f) - mu * mu;
        float rs  = rsqrtf(var + 1e-5f);
        uint2 p;
        p.x = pack2((x.x - mu) * rs * lw4.x + lb4.x, (x.y - mu) * rs * lw4.y + lb4.y);
        p.y = pack2((x.z - mu) * rs * lw4.z + lb4.z, (x.w - mu) * rs * lw4.w + lb4.w);
        *(uint2*)&mns[t * 72 + 4 * l] = p;
    }
    __syncthreads();

    #pragma unroll
    for (int i = 0; i < 4; ++i) {
        f4_t acc = {0.f, 0.f, 0.f, 0.f};
        #pragma unroll
        for (int kt = 0; kt < 2; ++kt) {
            bf8_t a = *(const bf8_t*)&mns[(mt * 16 + r16) * 72 + kt * 32 + quad * 8];
            acc = __builtin_amdgcn_mfma_f32_16x16x32_bf16(a, wg[i][kt], acc, 0, 0, 0);
        }
        int hc = (nb2 + i) * 16 + r16;
        float og = opl[hc], bgv = bgl[hc];
        #pragma unroll
        for (int ii = 0; ii < 4; ++ii) {
            int row = mt * 16 + quad * 4 + ii;
            float z  = acc[ii] + bgv;
            float gv = 1.f / (1.f + expf(-z));
            olds[row * 136 + hc] = f2b(og * gv);
        }
    }
    __syncthreads();

    #pragma unroll
    for (int i = 0; i < 2; ++i) {
        f4_t acc = {0.f, 0.f, 0.f, 0.f};
        #pragma unroll
        for (int kt = 0; kt < 4; ++kt) {
            bf8_t a = *(const bf8_t*)&olds[(mt * 16 + r16) * 136 + kt * 32 + quad * 8];
            acc = __builtin_amdgcn_mfma_f32_16x16x32_bf16(a, wo[i][kt], acc, 0, 0, 0);
        }
        int c = (nb3 + i) * 16 + r16;
        float bov = bol[c];
        #pragma unroll
        for (int ii = 0; ii < 4; ++ii) {
            int row = mt * 16 + quad * 4 + ii;
            outs[row * 68 + c] = acc[ii] + bov;
        }
    }
    __syncthreads();

    #pragma unroll
    for (int tt = 0; tt < 2; ++tt) {
        int t = g + tt * 16;
        int s = s0 + t;
        size_t base = ((size_t)s * R_ + r) * C_;
        *(float4*)&out[base + 4 * l] = *(const float4*)&outs[t * 68 + 4 * l];
    }
}

extern "C" void kernel_launch(void* const* d_in, const int* in_sizes, int n_in,
                              void* d_out, int out_size, void* d_ws, size_t ws_size,
                              hipStream_t stream)
{
    const float* m    = (const float*)d_in[0];
    const float* mask = (const float*)d_in[1];
    const float* lnw  = (const float*)d_in[2];
    const float* lnb  = (const float*)d_in[3];
    const float* Wq   = (const float*)d_in[4];
    const float* Wk   = (const float*)d_in[5];
    const float* Wv   = (const float*)d_in[6];
    const float* Wg   = (const float*)d_in[7];
    const float* bg   = (const float*)d_in[8];
    const float* Wo   = (const float*)d_in[9];
    const float* bo   = (const float*)d_in[10];
    float* out = (float*)d_out;

    char* ws = (char*)d_ws;
    u16*   kbuf  = (u16*)ws;                              // 32 MB
    u16*   vbuf  = (u16*)(ws + 33554432ull);              // 32 MB
    float* qsum  = (float*)(ws + 67108864ull);            // 128 KB
    float* msum  = (float*)(ws + 67239936ull);            // 2 KB
    float* opool = (float*)(ws + 67241984ull);            // 256 KB
    u16*   kvT   = (u16*)(ws + 67504128ull);              // 4 KB
    u16*   WgT   = (u16*)(ws + 67508224ull);              // 16 KB
    u16*   WoT   = (u16*)(ws + 67524608ull);              // 16 KB
    u16*   mns_g = (u16*)(ws + 67540992ull);              // 128 MB (optional)
    const size_t WS_NEED_MNS = 67540992ull + 134217728ull;
    const bool use_mns = ws_size >= WS_NEED_MNS;

    hipMemsetAsync(ws + 67108864ull, 0, 131072 + 2048, stream);
    k0<<<32, 256, 0, stream>>>(Wk, Wv, Wg, Wo, kvT, WgT, WoT);
    k1a<<<32768, 256, 0, stream>>>(m, mask, lnw, lnb, kvT, kbuf, vbuf, qsum, msum,
                                   use_mns ? mns_g : (u16*)nullptr);
    k1b<<<512, 256, 0, stream>>>(qsum, msum, Wq, mask, kbuf, vbuf, opool);
    if (use_mns)
        k2m<<<32768, 256, 0, stream>>>(mns_g, WgT, WoT, bg, bo, opool, out);
    else
        k2f<<<32768, 256, 0, stream>>>(m, lnw, lnb, WgT, WoT, bg, bo, opool, out);
}

// Round 2
// 827.316 us; speedup vs baseline: 1.2435x; 1.0265x over previous
//
#include <hip/hip_runtime.h>
#include <stdint.h>

#define S_ 2048
#define R_ 512
#define C_ 64

typedef unsigned short u16;
typedef __attribute__((ext_vector_type(8))) short bf8_t;   // 8 bf16 (4 VGPRs)
typedef __attribute__((ext_vector_type(4))) float f4_t;    // 4 fp32 acc

__device__ __forceinline__ u16 f2b(float f) {  // f32 -> bf16 RNE
    union { float f; unsigned int i; } x; x.f = f;
    unsigned int r = x.i + 0x7fffu + ((x.i >> 16) & 1u);
    return (u16)(r >> 16);
}
__device__ __forceinline__ unsigned int pack2(float a, float b) {
    return (unsigned int)f2b(a) | ((unsigned int)f2b(b) << 16);
}
__device__ __forceinline__ void u4_to_f8(uint4 p, float* f) {  // 8 bf16 -> 8 f32
    union { unsigned int i; float f; } x;
    x.i = p.x << 16;         f[0] = x.f;
    x.i = p.x & 0xffff0000u; f[1] = x.f;
    x.i = p.y << 16;         f[2] = x.f;
    x.i = p.y & 0xffff0000u; f[3] = x.f;
    x.i = p.z << 16;         f[4] = x.f;
    x.i = p.z & 0xffff0000u; f[5] = x.f;
    x.i = p.w << 16;         f[6] = x.f;
    x.i = p.w & 0xffff0000u; f[7] = x.f;
}

// ---------------- K0: one-time weight pre-convert to bf16 (B^T fragment layouts) ----
__global__ __launch_bounds__(256) void k0(
    const float* __restrict__ Wk, const float* __restrict__ Wv,
    const float* __restrict__ Wg, const float* __restrict__ Wo,
    u16* __restrict__ kvT, u16* __restrict__ WgT, u16* __restrict__ WoT)
{
    int i = blockIdx.x * 256 + threadIdx.x;      // 0..8191
    if (i < 2048) {                              // kvT[j][c], j in [0,32): k heads then v
        int j = i >> 6, c = i & 63;
        float w = (j < 16) ? Wk[c * 16 + j] : Wv[c * 16 + (j - 16)];
        kvT[i] = f2b(w);
    }
    {                                            // WgT[hc][c] = Wg[c][hc]
        int hc = i >> 6, c = i & 63;
        WgT[i] = f2b(Wg[c * 128 + hc]);
    }
    {                                            // WoT[c][hc] = Wo[hc][c]
        int c = i >> 7, hc = i & 127;
        WoT[i] = f2b(Wo[hc * 64 + c]);
    }
}

// ---------------- K1a: LN + qsum + (k,v) = mn @ [Wk|Wv] via MFMA ----------------
// grid: 32768 blocks (512 r x 64 s-chunks of 32 tokens), 256 threads
__global__ __launch_bounds__(256) void k1a(
    const float* __restrict__ m, const float* __restrict__ mask,
    const float* __restrict__ lnw_g, const float* __restrict__ lnb_g,
    const u16* __restrict__ kvT_g,
    u16* __restrict__ kbuf, u16* __restrict__ vbuf,
    float* __restrict__ qsum, float* __restrict__ msum,
    u16* __restrict__ mns_g)          // may be null (ws too small)
{
    __shared__ __attribute__((aligned(16))) u16 mns[32 * 72];   // [tok][c] bf16, pitch 72
    __shared__ __attribute__((aligned(16))) u16 kva[32 * 40];   // staging [tok][32] bf16
    __shared__ float qred[4][64];
    __shared__ float msred[4];

    const int tid = threadIdx.x;
    const int bi  = blockIdx.x;
    const int r   = bi >> 6;
    const int s0  = (bi & 63) << 5;
    const int wv = tid >> 6, lane = tid & 63;
    const int r16 = lane & 15, quad = lane >> 4;
    const int mt = wv & 1, nt = wv >> 1;

    // B fragments straight from global bf16 (L2-resident)
    bf8_t b0 = *(const bf8_t*)&kvT_g[(nt * 16 + r16) * 64 + quad * 8];
    bf8_t b1 = *(const bf8_t*)&kvT_g[(nt * 16 + r16) * 64 + 32 + quad * 8];

    const int g = tid >> 4, l = tid & 15;
    const float4 lw4 = *(const float4*)&lnw_g[4 * l];
    const float4 lb4 = *(const float4*)&lnb_g[4 * l];

    float4 qacc = {0.f, 0.f, 0.f, 0.f};
    float msacc = 0.f;
    #pragma unroll
    for (int tt = 0; tt < 2; ++tt) {
        int t = g + tt * 16;
        int s = s0 + t;
        size_t base = ((size_t)s * R_ + r) * C_;
        float4 x = *(const float4*)&m[base + 4 * l];
        float sum = x.x + x.y + x.z + x.w;
        float ssq = x.x * x.x + x.y * x.y + x.z * x.z + x.w * x.w;
        #pragma unroll
        for (int off = 1; off <= 8; off <<= 1) {
            sum += __shfl_xor(sum, off);
            ssq += __shfl_xor(ssq, off);
        }
        float mu  = sum * (1.f / 64.f);
        float var = ssq * (1.f / 64.f) - mu * mu;
        float rs  = rsqrtf(var + 1e-5f);
        float4 mn;
        mn.x = (x.x - mu) * rs * lw4.x + lb4.x;
        mn.y = (x.y - mu) * rs * lw4.y + lb4.y;
        mn.z = (x.z - mu) * rs * lw4.z + lb4.z;
        mn.w = (x.w - mu) * rs * lw4.w + lb4.w;
        float mk = mask[(size_t)s * R_ + r];
        qacc.x += mn.x * mk; qacc.y += mn.y * mk;
        qacc.z += mn.z * mk; qacc.w += mn.w * mk;
        if (l == 0) msacc += mk;
        uint2 p; p.x = pack2(mn.x, mn.y); p.y = pack2(mn.z, mn.w);
        *(uint2*)&mns[t * 72 + 4 * l] = p;
        if (mns_g)   // persist normalized tokens for k2 (bf16, [r][s][c])
            *(uint2*)&mns_g[((size_t)r * S_ + s) * C_ + 4 * l] = p;
    }
    qacc.x += __shfl_xor(qacc.x, 16); qacc.y += __shfl_xor(qacc.y, 16);
    qacc.z += __shfl_xor(qacc.z, 16); qacc.w += __shfl_xor(qacc.w, 16);
    qacc.x += __shfl_xor(qacc.x, 32); qacc.y += __shfl_xor(qacc.y, 32);
    qacc.z += __shfl_xor(qacc.z, 32); qacc.w += __shfl_xor(qacc.w, 32);
    msacc += __shfl_xor(msacc, 16);  msacc += __shfl_xor(msacc, 32);
    if (lane < 16) *(float4*)&qred[wv][4 * lane] = qacc;
    if (lane == 0) msred[wv] = msacc;
    __syncthreads();

    {
        f4_t acc = {0.f, 0.f, 0.f, 0.f};
        bf8_t a0 = *(const bf8_t*)&mns[(mt * 16 + r16) * 72 + quad * 8];
        bf8_t a1 = *(const bf8_t*)&mns[(mt * 16 + r16) * 72 + 32 + quad * 8];
        acc = __builtin_amdgcn_mfma_f32_16x16x32_bf16(a0, b0, acc, 0, 0, 0);
        acc = __builtin_amdgcn_mfma_f32_16x16x32_bf16(a1, b1, acc, 0, 0, 0);
        #pragma unroll
        for (int i = 0; i < 4; ++i) {
            int row = mt * 16 + quad * 4 + i;
            kva[row * 40 + nt * 16 + r16] = f2b(acc[i]);
        }
    }
    __syncthreads();

    for (int uidx = tid; uidx < 512; uidx += 256) {
        int t = uidx >> 4, u = uidx & 15;
        unsigned int val = *(const unsigned int*)&kva[t * 40 + u * 2];
        int s = s0 + t;
        size_t tb = ((size_t)r * S_ + s) * 16;
        if (u < 8) *(unsigned int*)&kbuf[tb + u * 2] = val;
        else       *(unsigned int*)&vbuf[tb + (u - 8) * 2] = val;
    }
    if (tid < 64) {
        float tot = qred[0][tid] + qred[1][tid] + qred[2][tid] + qred[3][tid];
        atomicAdd(&qsum[r * 64 + tid], tot);
    }
    if (tid == 0) atomicAdd(&msum[r], msred[0] + msred[1] + msred[2] + msred[3]);
}

// ---------------- K1bp: partial (online) softmax attention over a 256-token chunk ----
// grid: 4096 blocks (512 r x 8 chunks), 256 threads (wave w -> heads w and w+4)
// writes pbuf[r][h][chunk] = {m, l, o[16]}
__global__ __launch_bounds__(256) void k1bp(
    const float* __restrict__ qsum, const float* __restrict__ msum,
    const float* __restrict__ Wq, const float* __restrict__ mask,
    const u16* __restrict__ kbuf, const u16* __restrict__ vbuf,
    float* __restrict__ pbuf)
{
    __shared__ float qbar[64];
    __shared__ float qh[128];
    const int tid = threadIdx.x;
    const int bi  = blockIdx.x;
    const int r   = bi >> 3;
    const int ck  = bi & 7;

    if (tid < 64) qbar[tid] = qsum[r * 64 + tid] / (msum[r] + 1e-10f);
    __syncthreads();
    if (tid < 128) {
        float a = 0.f;
        #pragma unroll 8
        for (int c = 0; c < 64; ++c) a += qbar[c] * Wq[c * 128 + tid];
        qh[tid] = a * 0.25f;   // CH^-0.5
    }
    __syncthreads();

    const int wv = tid >> 6, lane = tid & 63;
    const int h0 = wv, h1 = wv + 4;
    float qa[16], qb[16];
    #pragma unroll
    for (int ch = 0; ch < 16; ++ch) { qa[ch] = qh[h0 * 16 + ch]; qb[ch] = qh[h1 * 16 + ch]; }

    const int sbase = ck * 256;
    // sweep 1: chunk max
    float m0 = -1e30f, m1 = -1e30f;
    #pragma unroll
    for (int i = 0; i < 4; ++i) {
        int s = sbase + i * 64 + lane;
        size_t tb = ((size_t)r * S_ + s) * 16;
        float kf[16];
        u4_to_f8(*(const uint4*)&kbuf[tb], kf);
        u4_to_f8(*(const uint4*)&kbuf[tb + 8], kf + 8);
        float bias = (mask[(size_t)s * R_ + r] - 1.f) * 1e9f;
        float a0 = bias, a1 = bias;
        #pragma unroll
        for (int ch = 0; ch < 16; ++ch) { a0 += qa[ch] * kf[ch]; a1 += qb[ch] * kf[ch]; }
        m0 = fmaxf(m0, a0); m1 = fmaxf(m1, a1);
    }
    #pragma unroll
    for (int off = 1; off < 64; off <<= 1) {
        m0 = fmaxf(m0, __shfl_xor(m0, off));
        m1 = fmaxf(m1, __shfl_xor(m1, off));
    }
    // sweep 2: exp-sum + weighted V (chunk-local max)
    float l0 = 0.f, l1 = 0.f;
    float o0[16], o1[16];
    #pragma unroll
    for (int ch = 0; ch < 16; ++ch) { o0[ch] = 0.f; o1[ch] = 0.f; }
    #pragma unroll
    for (int i = 0; i < 4; ++i) {
        int s = sbase + i * 64 + lane;
        size_t tb = ((size_t)r * S_ + s) * 16;
        float kf[16], vf[16];
        u4_to_f8(*(const uint4*)&kbuf[tb], kf);
        u4_to_f8(*(const uint4*)&kbuf[tb + 8], kf + 8);
        u4_to_f8(*(const uint4*)&vbuf[tb], vf);
        u4_to_f8(*(const uint4*)&vbuf[tb + 8], vf + 8);
        float bias = (mask[(size_t)s * R_ + r] - 1.f) * 1e9f;
        float a0 = bias, a1 = bias;
        #pragma unroll
        for (int ch = 0; ch < 16; ++ch) { a0 += qa[ch] * kf[ch]; a1 += qb[ch] * kf[ch]; }
        float w0 = __expf(a0 - m0), w1 = __expf(a1 - m1);
        l0 += w0; l1 += w1;
        #pragma unroll
        for (int ch = 0; ch < 16; ++ch) { o0[ch] += w0 * vf[ch]; o1[ch] += w1 * vf[ch]; }
    }
    #pragma unroll
    for (int off = 1; off < 64; off <<= 1) {
        l0 += __shfl_xor(l0, off); l1 += __shfl_xor(l1, off);
        #pragma unroll
        for (int ch = 0; ch < 16; ++ch) {
            o0[ch] += __shfl_xor(o0[ch], off);
            o1[ch] += __shfl_xor(o1[ch], off);
        }
    }
    if (lane == 0) {
        size_t p0 = (((size_t)r * 8 + h0) * 8 + ck) * 18;
        size_t p1 = (((size_t)r * 8 + h1) * 8 + ck) * 18;
        pbuf[p0] = m0; pbuf[p0 + 1] = l0;
        pbuf[p1] = m1; pbuf[p1 + 1] = l1;
        #pragma unroll
        for (int ch = 0; ch < 16; ++ch) {
            pbuf[p0 + 2 + ch] = o0[ch];
            pbuf[p1 + 2 + ch] = o1[ch];
        }
    }
}

// ---------------- K1c: merge 8 chunk-partials per (r, head) -> opool ----------------
// grid: 512 blocks x 128 threads (thread = h*16+ch)
__global__ __launch_bounds__(128) void k1c(
    const float* __restrict__ pbuf, float* __restrict__ opool)
{
    const int r = blockIdx.x;
    const int tid = threadIdx.x;       // 0..127
    const int h = tid >> 4, ch = tid & 15;
    size_t base = (((size_t)r * 8 + h) * 8) * 18;
    float M = -1e30f;
    #pragma unroll
    for (int i = 0; i < 8; ++i) M = fmaxf(M, pbuf[base + i * 18]);
    float L = 0.f, O = 0.f;
    #pragma unroll
    for (int i = 0; i < 8; ++i) {
        float sc = __expf(pbuf[base + i * 18] - M);
        L += pbuf[base + i * 18 + 1] * sc;
        O += pbuf[base + i * 18 + 2 + ch] * sc;
    }
    opool[r * 128 + tid] = O / L;
}

// ---------------- K1b_mono: fallback single-block-per-r global softmax ----------------
__global__ __launch_bounds__(256) void k1b_mono(
    const float* __restrict__ qsum, const float* __restrict__ msum,
    const float* __restrict__ Wq, const float* __restrict__ mask,
    const u16* __restrict__ kbuf, const u16* __restrict__ vbuf,
    float* __restrict__ opool)
{
    __shared__ float qbar[64];
    __shared__ float qh[128];
    const int tid = threadIdx.x;
    const int r   = blockIdx.x;

    if (tid < 64) qbar[tid] = qsum[r * 64 + tid] / (msum[r] + 1e-10f);
    __syncthreads();
    if (tid < 128) {
        float a = 0.f;
        #pragma unroll 8
        for (int c = 0; c < 64; ++c) a += qbar[c] * Wq[c * 128 + tid];
        qh[tid] = a * 0.25f;
    }
    __syncthreads();

    const int wv = tid >> 6, lane = tid & 63;
    const int h0 = wv, h1 = wv + 4;
    float qa[16], qb[16];
    #pragma unroll
    for (int ch = 0; ch < 16; ++ch) { qa[ch] = qh[h0 * 16 + ch]; qb[ch] = qh[h1 * 16 + ch]; }

    float m0 = -1e30f, m1 = -1e30f;
    for (int i = 0; i < 32; ++i) {
        int s = i * 64 + lane;
        size_t tb = ((size_t)r * S_ + s) * 16;
        float kf[16];
        u4_to_f8(*(const uint4*)&kbuf[tb], kf);
        u4_to_f8(*(const uint4*)&kbuf[tb + 8], kf + 8);
        float bias = (mask[(size_t)s * R_ + r] - 1.f) * 1e9f;
        float a0 = bias, a1 = bias;
        #pragma unroll
        for (int ch = 0; ch < 16; ++ch) { a0 += qa[ch] * kf[ch]; a1 += qb[ch] * kf[ch]; }
        m0 = fmaxf(m0, a0); m1 = fmaxf(m1, a1);
    }
    #pragma unroll
    for (int off = 1; off < 64; off <<= 1) {
        m0 = fmaxf(m0, __shfl_xor(m0, off));
        m1 = fmaxf(m1, __shfl_xor(m1, off));
    }
    float l0 = 0.f, l1 = 0.f;
    float o0[16], o1[16];
    #pragma unroll
    for (int ch = 0; ch < 16; ++ch) { o0[ch] = 0.f; o1[ch] = 0.f; }
    for (int i = 0; i < 32; ++i) {
        int s = i * 64 + lane;
        size_t tb = ((size_t)r * S_ + s) * 16;
        float kf[16], vf[16];
        u4_to_f8(*(const uint4*)&kbuf[tb], kf);
        u4_to_f8(*(const uint4*)&kbuf[tb + 8], kf + 8);
        u4_to_f8(*(const uint4*)&vbuf[tb], vf);
        u4_to_f8(*(const uint4*)&vbuf[tb + 8], vf + 8);
        float bias = (mask[(size_t)s * R_ + r] - 1.f) * 1e9f;
        float a0 = bias, a1 = bias;
        #pragma unroll
        for (int ch = 0; ch < 16; ++ch) { a0 += qa[ch] * kf[ch]; a1 += qb[ch] * kf[ch]; }
        float w0 = __expf(a0 - m0), w1 = __expf(a1 - m1);
        l0 += w0; l1 += w1;
        #pragma unroll
        for (int ch = 0; ch < 16; ++ch) { o0[ch] += w0 * vf[ch]; o1[ch] += w1 * vf[ch]; }
    }
    #pragma unroll
    for (int off = 1; off < 64; off <<= 1) {
        l0 += __shfl_xor(l0, off); l1 += __shfl_xor(l1, off);
        #pragma unroll
        for (int ch = 0; ch < 16; ++ch) {
            o0[ch] += __shfl_xor(o0[ch], off);
            o1[ch] += __shfl_xor(o1[ch], off);
        }
    }
    if (lane == 0) {
        float inv0 = 1.f / l0, inv1 = 1.f / l1;
        #pragma unroll
        for (int ch = 0; ch < 16; ++ch) {
            opool[r * 128 + h0 * 16 + ch] = o0[ch] * inv0;
            opool[r * 128 + h1 * 16 + ch] = o1[ch] * inv1;
        }
    }
}

// ---------------- K2m: g=sigmoid(mns@Wg+bg), out = (opool*g)@Wo + bo ----------------
// grid: 32768 blocks, 256 threads; reads persisted bf16 mns; weights in registers
__global__ __launch_bounds__(256) void k2m(
    const u16* __restrict__ mns_g,
    const u16* __restrict__ WgT_g, const u16* __restrict__ WoT_g,
    const float* __restrict__ bg, const float* __restrict__ bo,
    const float* __restrict__ opool, float* __restrict__ out)
{
    __shared__ __attribute__((aligned(16))) u16 olds[32 * 136];  // [tok][hc] bf16
    __shared__ __attribute__((aligned(16))) float outs[32 * 68]; // [tok][c] f32
    __shared__ float opl[128], bgl[128];
    __shared__ float bol[64];

    const int tid = threadIdx.x;
    const int bi  = blockIdx.x;
    const int r   = bi >> 6;
    const int s0  = (bi & 63) << 5;
    const int wv = tid >> 6, lane = tid & 63;
    const int r16 = lane & 15, quad = lane >> 4;

    const int mt  = wv >> 1;          // token sub-tile for both steps
    const int nb2 = (wv & 1) * 4;     // step2: nt = nb2..nb2+3
    const int nb3 = (wv & 1) * 2;     // step3: nt = nb3..nb3+1

    bf8_t wg[4][2], wo[2][4];
    #pragma unroll
    for (int i = 0; i < 4; ++i)
        #pragma unroll
        for (int kt = 0; kt < 2; ++kt)
            wg[i][kt] = *(const bf8_t*)&WgT_g[((nb2 + i) * 16 + r16) * 64 + kt * 32 + quad * 8];
    #pragma unroll
    for (int i = 0; i < 2; ++i)
        #pragma unroll
        for (int kt = 0; kt < 4; ++kt)
            wo[i][kt] = *(const bf8_t*)&WoT_g[((nb3 + i) * 16 + r16) * 128 + kt * 32 + quad * 8];

    size_t abase = ((size_t)r * S_ + s0 + mt * 16 + r16) * C_;
    bf8_t a0 = *(const bf8_t*)&mns_g[abase + quad * 8];
    bf8_t a1 = *(const bf8_t*)&mns_g[abase + 32 + quad * 8];

    if (tid < 128) { opl[tid] = opool[r * 128 + tid]; bgl[tid] = bg[tid]; }
    if (tid < 64)  { bol[tid] = bo[tid]; }
    __syncthreads();

    // step 2: z = mns[32x64] @ Wg[64x128]; fast sigmoid gate; olds = opool*g (bf16)
    #pragma unroll
    for (int i = 0; i < 4; ++i) {
        f4_t acc = {0.f, 0.f, 0.f, 0.f};
        acc = __builtin_amdgcn_mfma_f32_16x16x32_bf16(a0, wg[i][0], acc, 0, 0, 0);
        acc = __builtin_amdgcn_mfma_f32_16x16x32_bf16(a1, wg[i][1], acc, 0, 0, 0);
        int hc = (nb2 + i) * 16 + r16;
        float og = opl[hc], bgv = bgl[hc];
        #pragma unroll
        for (int ii = 0; ii < 4; ++ii) {
            int row = mt * 16 + quad * 4 + ii;
            float z  = acc[ii] + bgv;
            float gv = __builtin_amdgcn_rcpf(1.f + __expf(-z));
            olds[row * 136 + hc] = f2b(og * gv);
        }
    }
    __syncthreads();

    // step 3: out = o[32x128] @ Wo[128x64]
    #pragma unroll
    for (int i = 0; i < 2; ++i) {
        f4_t acc = {0.f, 0.f, 0.f, 0.f};
        #pragma unroll
        for (int kt = 0; kt < 4; ++kt) {
            bf8_t a = *(const bf8_t*)&olds[(mt * 16 + r16) * 136 + kt * 32 + quad * 8];
            acc = __builtin_amdgcn_mfma_f32_16x16x32_bf16(a, wo[i][kt], acc, 0, 0, 0);
        }
        int c = (nb3 + i) * 16 + r16;
        float bov = bol[c];
        #pragma unroll
        for (int ii = 0; ii < 4; ++ii) {
            int row = mt * 16 + quad * 4 + ii;
            outs[row * 68 + c] = acc[ii] + bov;
        }
    }
    __syncthreads();

    const int g = tid >> 4, l = tid & 15;
    #pragma unroll
    for (int tt = 0; tt < 2; ++tt) {
        int t = g + tt * 16;
        int s = s0 + t;
        size_t base = ((size_t)s * R_ + r) * C_;
        *(float4*)&out[base + 4 * l] = *(const float4*)&outs[t * 68 + 4 * l];
    }
}

// ---------------- K2f: fallback (ws too small for mns) — LN from m, reg weights ----
__global__ __launch_bounds__(256) void k2f(
    const float* __restrict__ m,
    const float* __restrict__ lnw_g, const float* __restrict__ lnb_g,
    const u16* __restrict__ WgT_g, const u16* __restrict__ WoT_g,
    const float* __restrict__ bg, const float* __restrict__ bo,
    const float* __restrict__ opool, float* __restrict__ out)
{
    __shared__ __attribute__((aligned(16))) u16 mns[32 * 72];
    __shared__ __attribute__((aligned(16))) u16 olds[32 * 136];
    __shared__ __attribute__((aligned(16))) float outs[32 * 68];
    __shared__ float opl[128], bgl[128];
    __shared__ float bol[64];

    const int tid = threadIdx.x;
    const int bi  = blockIdx.x;
    const int r   = bi >> 6;
    const int s0  = (bi & 63) << 5;
    const int wv = tid >> 6, lane = tid & 63;
    const int r16 = lane & 15, quad = lane >> 4;
    const int mt  = wv >> 1;
    const int nb2 = (wv & 1) * 4;
    const int nb3 = (wv & 1) * 2;

    bf8_t wg[4][2], wo[2][4];
    #pragma unroll
    for (int i = 0; i < 4; ++i)
        #pragma unroll
        for (int kt = 0; kt < 2; ++kt)
            wg[i][kt] = *(const bf8_t*)&WgT_g[((nb2 + i) * 16 + r16) * 64 + kt * 32 + quad * 8];
    #pragma unroll
    for (int i = 0; i < 2; ++i)
        #pragma unroll
        for (int kt = 0; kt < 4; ++kt)
            wo[i][kt] = *(const bf8_t*)&WoT_g[((nb3 + i) * 16 + r16) * 128 + kt * 32 + quad * 8];

    if (tid < 128) { opl[tid] = opool[r * 128 + tid]; bgl[tid] = bg[tid]; }
    if (tid < 64)  { bol[tid] = bo[tid]; }

    const int g = tid >> 4, l = tid & 15;
    const float4 lw4 = *(const float4*)&lnw_g[4 * l];
    const float4 lb4 = *(const float4*)&lnb_g[4 * l];
    #pragma unroll
    for (int tt = 0; tt < 2; ++tt) {
        int t = g + tt * 16;
        int s = s0 + t;
        size_t base = ((size_t)s * R_ + r) * C_;
        float4 x = *(const float4*)&m[base + 4 * l];
        float sum = x.x + x.y + x.z + x.w;
        float ssq = x.x * x.x + x.y * x.y + x.z * x.z + x.w * x.w;
        #pragma unroll
        for (int off = 1; off <= 8; off <<= 1) {
            sum += __shfl_xor(sum, off);
            ssq += __shfl_xor(ssq, off);
        }
        float mu  = sum * (1.f / 64.f);
        float var = ssq * (1.f / 64.f) - mu * mu;
        float rs  = rsqrtf(var + 1e-5f);
        uint2 p;
        p.x = pack2((x.x - mu) * rs * lw4.x + lb4.x, (x.y - mu) * rs * lw4.y + lb4.y);
        p.y = pack2((x.z - mu) * rs * lw4.z + lb4.z, (x.w - mu) * rs * lw4.w + lb4.w);
        *(uint2*)&mns[t * 72 + 4 * l] = p;
    }
    __syncthreads();

    #pragma unroll
    for (int i = 0; i < 4; ++i) {
        f4_t acc = {0.f, 0.f, 0.f, 0.f};
        #pragma unroll
        for (int kt = 0; kt < 2; ++kt) {
            bf8_t a = *(const bf8_t*)&mns[(mt * 16 + r16) * 72 + kt * 32 + quad * 8];
            acc = __builtin_amdgcn_mfma_f32_16x16x32_bf16(a, wg[i][kt], acc, 0, 0, 0);
        }
        int hc = (nb2 + i) * 16 + r16;
        float og = opl[hc], bgv = bgl[hc];
        #pragma unroll
        for (int ii = 0; ii < 4; ++ii) {
            int row = mt * 16 + quad * 4 + ii;
            float z  = acc[ii] + bgv;
            float gv = __builtin_amdgcn_rcpf(1.f + __expf(-z));
            olds[row * 136 + hc] = f2b(og * gv);
        }
    }
    __syncthreads();

    #pragma unroll
    for (int i = 0; i < 2; ++i) {
        f4_t acc = {0.f, 0.f, 0.f, 0.f};
        #pragma unroll
        for (int kt = 0; kt < 4; ++kt) {
            bf8_t a = *(const bf8_t*)&olds[(mt * 16 + r16) * 136 + kt * 32 + quad * 8];
            acc = __builtin_amdgcn_mfma_f32_16x16x32_bf16(a, wo[i][kt], acc, 0, 0, 0);
        }
        int c = (nb3 + i) * 16 + r16;
        float bov = bol[c];
        #pragma unroll
        for (int ii = 0; ii < 4; ++ii) {
            int row = mt * 16 + quad * 4 + ii;
            outs[row * 68 + c] = acc[ii] + bov;
        }
    }
    __syncthreads();

    #pragma unroll
    for (int tt = 0; tt < 2; ++tt) {
        int t = g + tt * 16;
        int s = s0 + t;
        size_t base = ((size_t)s * R_ + r) * C_;
        *(float4*)&out[base + 4 * l] = *(const float4*)&outs[t * 68 + 4 * l];
    }
}

extern "C" void kernel_launch(void* const* d_in, const int* in_sizes, int n_in,
                              void* d_out, int out_size, void* d_ws, size_t ws_size,
                              hipStream_t stream)
{
    const float* m    = (const float*)d_in[0];
    const float* mask = (const float*)d_in[1];
    const float* lnw  = (const float*)d_in[2];
    const float* lnb  = (const float*)d_in[3];
    const float* Wq   = (const float*)d_in[4];
    const float* Wk   = (const float*)d_in[5];
    const float* Wv   = (const float*)d_in[6];
    const float* Wg   = (const float*)d_in[7];
    const float* bg   = (const float*)d_in[8];
    const float* Wo   = (const float*)d_in[9];
    const float* bo   = (const float*)d_in[10];
    float* out = (float*)d_out;

    char* ws = (char*)d_ws;
    u16*   kbuf  = (u16*)ws;                              // 32 MB
    u16*   vbuf  = (u16*)(ws + 33554432ull);              // 32 MB
    float* qsum  = (float*)(ws + 67108864ull);            // 128 KB
    float* msum  = (float*)(ws + 67239936ull);            // 2 KB
    float* opool = (float*)(ws + 67241984ull);            // 256 KB
    u16*   kvT   = (u16*)(ws + 67504128ull);              // 4 KB
    u16*   WgT   = (u16*)(ws + 67508224ull);              // 16 KB
    u16*   WoT   = (u16*)(ws + 67524608ull);              // 16 KB
    u16*   mns_g = (u16*)(ws + 67540992ull);              // 128 MB (optional)
    float* pbuf  = (float*)(ws + 201758720ull);           // 2.25 MB (optional)
    const size_t NEED_MNS = 67540992ull + 134217728ull;   // 201758720
    const size_t NEED_PB  = 201758720ull + 2359296ull;    // 204118016
    const bool use_mns = ws_size >= NEED_MNS;
    const bool use_pb  = ws_size >= NEED_PB;

    hipMemsetAsync(ws + 67108864ull, 0, 131072 + 2048, stream);
    k0<<<32, 256, 0, stream>>>(Wk, Wv, Wg, Wo, kvT, WgT, WoT);
    k1a<<<32768, 256, 0, stream>>>(m, mask, lnw, lnb, kvT, kbuf, vbuf, qsum, msum,
                                   use_mns ? mns_g : (u16*)nullptr);
    if (use_pb) {
        k1bp<<<4096, 256, 0, stream>>>(qsum, msum, Wq, mask, kbuf, vbuf, pbuf);
        k1c<<<512, 128, 0, stream>>>(pbuf, opool);
    } else {
        k1b_mono<<<512, 256, 0, stream>>>(qsum, msum, Wq, mask, kbuf, vbuf, opool);
    }
    if (use_mns)
        k2m<<<32768, 256, 0, stream>>>(mns_g, WgT, WoT, bg, bo, opool, out);
    else
        k2f<<<32768, 256, 0, stream>>>(m, lnw, lnb, WgT, WoT, bg, bo, opool, out);
}